// Round 6
// baseline (261.335 us; speedup 1.0000x reference)
//
#include <hip/hip_runtime.h>
#include <cstdint>

#define S_LEN 1024
#define C_DIM 2048
#define NH    16
#define NHK   4
#define HD    128
#define ROT   32
#define SCALE 0.08838834764831845f  // 1/sqrt(128)

typedef __bf16 bf16x8 __attribute__((ext_vector_type(8)));
typedef float floatx4 __attribute__((ext_vector_type(4)));
typedef float floatx16 __attribute__((ext_vector_type(16)));
typedef unsigned short ushortx8 __attribute__((ext_vector_type(8)));

__device__ __forceinline__ unsigned short f2bf(float f) {
  union { float f; uint32_t u; } x; x.f = f;
  uint32_t r = (x.u + 0x7fffu + ((x.u >> 16) & 1u)) >> 16;
  return (unsigned short)r;
}
__device__ __forceinline__ float bf2f(unsigned short v) {
  union { uint32_t u; float f; } x; x.u = (uint32_t)v << 16; return x.f;
}

__device__ __forceinline__ void async_copy16(const unsigned short* g, unsigned short* l) {
  __builtin_amdgcn_global_load_lds(
      (const __attribute__((address_space(1))) void*)g,
      (__attribute__((address_space(3))) void*)l,
      16, 0, 0);
}

// ---------------- fused weight cast f32 -> bf16 ----------------
__global__ void cast_all_kernel(const float* __restrict__ qw, const float* __restrict__ kw,
                                const float* __restrict__ vw, const float* __restrict__ ow,
                                unsigned short* __restrict__ out) {
  const int NQ = 4096 * 2048 / 4, NK = 512 * 2048 / 4, NV = 512 * 2048 / 4;
  int i = blockIdx.x * blockDim.x + threadIdx.x;
  const float* src; int j;
  if (i < NQ) { src = qw; j = i; }
  else if (i < NQ + NK) { src = kw; j = i - NQ; }
  else if (i < NQ + NK + NV) { src = vw; j = i - NQ - NK; }
  else { src = ow; j = i - NQ - NK - NV; }
  float4 v = ((const float4*)src)[j];
  ushort4 o;
  o.x = f2bf(v.x); o.y = f2bf(v.y); o.z = f2bf(v.z); o.w = f2bf(v.w);
  ((ushort4*)out)[i] = o;
}

// ---------------- transpose + cast x (C,S) -> xT (S,C) bf16 ----------------
__global__ __launch_bounds__(256)
void transpose_cast_x_kernel(const float* __restrict__ x, unsigned short* __restrict__ xT) {
  __shared__ float t[32][33];
  int st = blockIdx.x, ct = blockIdx.y;
  int c = threadIdx.x & 31, rq = threadIdx.x >> 5;
#pragma unroll
  for (int i = 0; i < 4; ++i) {
    int r = rq + i * 8;
    t[r][c] = x[(size_t)(ct * 32 + r) * S_LEN + st * 32 + c];
  }
  __syncthreads();
#pragma unroll
  for (int i = 0; i < 4; ++i) {
    int r = rq + i * 8;
    xT[(size_t)(st * 32 + r) * C_DIM + ct * 32 + c] = f2bf(t[c][r]);
  }
}

// ---------------- RMSNorm+RoPE epilogue (32x32 C/D layout, 1 ni) ------------
// acc[mi][reg]: row d = wm + mi*32 + (reg&3) + 8*(reg>>2) + 4*half,
//               col s = scol0 + l31
__device__ __forceinline__ void norm_rope_epi(
    floatx16 (&acc)[2], float (*pp)[32],
    const float* __restrict__ w, const int* __restrict__ pos_ids,
    const float* __restrict__ cosc, const float* __restrict__ sinc,
    unsigned short* __restrict__ outp,  // (S, D) for this head
    int wave, int lane, int wm, int scol0) {
  int l31 = lane & 31, half = lane >> 5;
  float s = 0.f;
#pragma unroll
  for (int mi = 0; mi < 2; ++mi)
#pragma unroll
    for (int reg = 0; reg < 16; ++reg) { float v = acc[mi][reg]; s += v * v; }
  s += __shfl_xor(s, 32);   // other half: disjoint 32 rows, same column
  if (half == 0) pp[wave][l31] = s;
  __syncthreads();
  float rn = rsqrtf((pp[wave][l31] + pp[wave ^ 1][l31]) * (1.0f / 128.0f) + 1e-6f);
  int scol = scol0 + l31;
  int pos = pos_ids[scol];
#pragma unroll
  for (int mi = 0; mi < 2; ++mi) {
    bool rope = (wm == 0) && (mi == 0);
#pragma unroll
    for (int g = 0; g < 4; ++g) {
      int dbase = wm + mi * 32 + half * 4 + g * 8;
      ushort4 o;
#pragma unroll
      for (int rr = 0; rr < 4; ++rr) {
        int reg = g * 4 + rr;
        int d = dbase + rr;
        float v = acc[mi][reg] * rn * (1.0f + w[d]);
        if (rope) {  // rows 0..31 exactly
          float cv = cosc[pos * ROT + d], sv = sinc[pos * ROT + d];
          int d2 = (d < 16) ? d + 16 : d - 16;
          float pv = acc[mi][reg ^ 8] * rn * (1.0f + w[d2]);
          v = v * cv + ((d < 16) ? -pv : pv) * sv;
        }
        ((unsigned short*)&o)[rr] = f2bf(v);
      }
      *(ushort4*)&outp[(size_t)scol * HD + dbase] = o;
    }
  }
}

// ---------------- QKV GEMM 128x64 tile, dbuf LDS, 32x32x16 MFMA -------------
// A = wqkv (5120,2048), BT = xT (1024,2048). Grid (16, 40) = 640 blocks.
// 4 waves: wm=(wave&1)*64 (2 mi), wn=(wave>>1)*32 (1 ni).
__global__ __launch_bounds__(256, 2)
void gemm_qkv_fused(const unsigned short* __restrict__ A,
                    const unsigned short* __restrict__ BT,
                    const float* __restrict__ qw, const float* __restrict__ kw,
                    const int* __restrict__ pos_ids,
                    const float* __restrict__ cosc, const float* __restrict__ sinc,
                    unsigned short* __restrict__ qb, unsigned short* __restrict__ kbuf,
                    unsigned short* __restrict__ vTb, unsigned short* __restrict__ sgb) {
  __shared__ unsigned short Asm[2][128 * 64];
  __shared__ unsigned short Bsm[2][64 * 64];
  __shared__ float pp[4][32];
  int tid = threadIdx.x, wave = tid >> 6, lane = tid & 63;
  int l31 = lane & 31, half = lane >> 5;
  int wm = (wave & 1) * 64, wn = (wave >> 1) * 32;
  int m0 = blockIdx.y * 128, n0 = blockIdx.x * 64;
  int r8 = lane >> 3, c8 = lane & 7;
  const unsigned short* Ag = A + (size_t)m0 * C_DIM;
  const unsigned short* Bg = BT + (size_t)n0 * C_DIM;
  floatx16 acc[2];
  acc[0] = (floatx16)0.f; acc[1] = (floatx16)0.f;

  auto stage = [&](int kt, int b) {
    // A rows [wave*32, +32): 4 issues of 8 rows x 128B, XOR-swizzled chunks
#pragma unroll
    for (int i = 0; i < 4; ++i) {
      int row = wave * 32 + i * 8 + r8;
      int cs = c8 ^ (row & 7);
      async_copy16(Ag + (size_t)row * C_DIM + kt + cs * 8, &Asm[b][(wave * 32 + i * 8) * 64]);
    }
    // B rows [wave*16, +16): 2 issues
#pragma unroll
    for (int i = 0; i < 2; ++i) {
      int row = wave * 16 + i * 8 + r8;
      int cs = c8 ^ (row & 7);
      async_copy16(Bg + (size_t)row * C_DIM + kt + cs * 8, &Bsm[b][(wave * 16 + i * 8) * 64]);
    }
  };

  stage(0, 0);
  __syncthreads();
  for (int t = 0; t < 32; ++t) {
    int b = t & 1;
    if (t < 31) stage((t + 1) * 64, b ^ 1);   // async prefetch overlaps compute
#pragma unroll
    for (int kb = 0; kb < 4; ++kb) {
      int co = (((kb << 1) | half) ^ (l31 & 7)) << 3;
      bf16x8 a0 = *(const bf16x8*)&Asm[b][(wm + l31) * 64 + co];
      bf16x8 a1 = *(const bf16x8*)&Asm[b][(wm + 32 + l31) * 64 + co];
      bf16x8 bf = *(const bf16x8*)&Bsm[b][(wn + l31) * 64 + co];
      acc[0] = __builtin_amdgcn_mfma_f32_32x32x16_bf16(a0, bf, acc[0], 0, 0, 0);
      acc[1] = __builtin_amdgcn_mfma_f32_32x32x16_bf16(a1, bf, acc[1], 0, 0, 0);
    }
    __syncthreads();
  }

  int scol0 = n0 + wn;
  int ty = blockIdx.y;
  if (ty < 32) {
    int h = ty >> 1;
    if ((ty & 1) == 0) {
      norm_rope_epi(acc, pp, qw, pos_ids, cosc, sinc,
                    qb + (size_t)h * S_LEN * HD, wave, lane, wm, scol0);
    } else {
      // gate rows: sigmoid -> sgb (h,S,D) bf16
      int scol = scol0 + l31;
#pragma unroll
      for (int mi = 0; mi < 2; ++mi)
#pragma unroll
        for (int g = 0; g < 4; ++g) {
          int dbase = wm + mi * 32 + half * 4 + g * 8;
          ushort4 o;
#pragma unroll
          for (int rr = 0; rr < 4; ++rr)
            ((unsigned short*)&o)[rr] = f2bf(1.0f / (1.0f + __expf(-acc[mi][g * 4 + rr])));
          *(ushort4*)&sgb[((size_t)h * S_LEN + scol) * HD + dbase] = o;
        }
    }
  } else if (ty < 36) {
    int hk = ty - 32;
    norm_rope_epi(acc, pp, kw, pos_ids, cosc, sinc,
                  kbuf + (size_t)hk * S_LEN * HD, wave, lane, wm, scol0);
  } else {
    int hk = ty - 36;  // v: rows are d, cols are s -> vTb (hk,D,S)
#pragma unroll
    for (int mi = 0; mi < 2; ++mi)
#pragma unroll
      for (int reg = 0; reg < 16; ++reg) {
        int d = wm + mi * 32 + (reg & 3) + 8 * (reg >> 2) + 4 * half;
        vTb[(size_t)hk * HD * S_LEN + (size_t)d * S_LEN + scol0 + l31] = f2bf(acc[mi][reg]);
      }
  }
}

// ---------------- O-proj GEMM: 128x64 tile, dbuf, split-K 2 -----------------
// Grid (16, 16, 2) = 512 blocks. Partials f32.
__global__ __launch_bounds__(256, 2)
void gemm_oproj_sk(const unsigned short* __restrict__ A,
                   const unsigned short* __restrict__ BT,
                   float* __restrict__ Pp) {
  __shared__ unsigned short Asm[2][128 * 64];
  __shared__ unsigned short Bsm[2][64 * 64];
  int tid = threadIdx.x, wave = tid >> 6, lane = tid & 63;
  int l31 = lane & 31, half = lane >> 5;
  int wm = (wave & 1) * 64, wn = (wave >> 1) * 32;
  int m0 = blockIdx.y * 128, n0 = blockIdx.x * 64;
  int kz0 = blockIdx.z * 1024;
  int r8 = lane >> 3, c8 = lane & 7;
  const unsigned short* Ag = A + (size_t)m0 * C_DIM;
  const unsigned short* Bg = BT + (size_t)n0 * C_DIM;
  floatx16 acc[2];
  acc[0] = (floatx16)0.f; acc[1] = (floatx16)0.f;

  auto stage = [&](int kt, int b) {
#pragma unroll
    for (int i = 0; i < 4; ++i) {
      int row = wave * 32 + i * 8 + r8;
      int cs = c8 ^ (row & 7);
      async_copy16(Ag + (size_t)row * C_DIM + kt + cs * 8, &Asm[b][(wave * 32 + i * 8) * 64]);
    }
#pragma unroll
    for (int i = 0; i < 2; ++i) {
      int row = wave * 16 + i * 8 + r8;
      int cs = c8 ^ (row & 7);
      async_copy16(Bg + (size_t)row * C_DIM + kt + cs * 8, &Bsm[b][(wave * 16 + i * 8) * 64]);
    }
  };

  stage(kz0, 0);
  __syncthreads();
  for (int t = 0; t < 16; ++t) {
    int b = t & 1;
    if (t < 15) stage(kz0 + (t + 1) * 64, b ^ 1);
#pragma unroll
    for (int kb = 0; kb < 4; ++kb) {
      int co = (((kb << 1) | half) ^ (l31 & 7)) << 3;
      bf16x8 a0 = *(const bf16x8*)&Asm[b][(wm + l31) * 64 + co];
      bf16x8 a1 = *(const bf16x8*)&Asm[b][(wm + 32 + l31) * 64 + co];
      bf16x8 bf = *(const bf16x8*)&Bsm[b][(wn + l31) * 64 + co];
      acc[0] = __builtin_amdgcn_mfma_f32_32x32x16_bf16(a0, bf, acc[0], 0, 0, 0);
      acc[1] = __builtin_amdgcn_mfma_f32_32x32x16_bf16(a1, bf, acc[1], 0, 0, 0);
    }
    __syncthreads();
  }
  float* base = Pp + (size_t)blockIdx.z * C_DIM * S_LEN;
#pragma unroll
  for (int mi = 0; mi < 2; ++mi)
#pragma unroll
    for (int reg = 0; reg < 16; ++reg) {
      int row = m0 + wm + mi * 32 + (reg & 3) + 8 * (reg >> 2) + 4 * half;
      base[(size_t)row * S_LEN + n0 + wn + l31] = acc[mi][reg];
    }
}

__global__ void reduce_oproj_kernel(const float* __restrict__ Pp, float* __restrict__ out) {
  int i = blockIdx.x * blockDim.x + threadIdx.x;
  const float4 a = ((const float4*)Pp)[i];
  const float4 b = ((const float4*)(Pp + (size_t)C_DIM * S_LEN))[i];
  float4 o; o.x = a.x + b.x; o.y = a.y + b.y; o.z = a.z + b.z; o.w = a.w + b.w;
  ((float4*)out)[i] = o;
}

// ---------------- MFMA flash attention, LDS-staged, 64 queries/block --------
__global__ __launch_bounds__(256)
void attn_kernel(const unsigned short* __restrict__ qb,
                 const unsigned short* __restrict__ kbuf,
                 const unsigned short* __restrict__ vTb,
                 const unsigned short* __restrict__ sgb,
                 unsigned short* __restrict__ outT) {
  __shared__ __align__(16) unsigned short Ks[64 * 128];   // [key][d], swizzled
  __shared__ __align__(16) unsigned short Vs[128 * 64];   // [d][key], swizzled
  __shared__ __align__(16) unsigned short Ps[4][16][72];
  int h = blockIdx.x, qt = blockIdx.y;
  int s0 = qt * 64;
  int hk = h >> 2;
  int tid = threadIdx.x, wave = tid >> 6, lane = tid & 63;
  int l16 = lane & 15, quad = lane >> 4;
  int lsw = l16 & 7;

  const unsigned short* qg = qb + ((size_t)(h * S_LEN + s0 + wave * 16 + l16)) * HD;
  bf16x8 qfr[4];
#pragma unroll
  for (int kb = 0; kb < 4; ++kb)
    qfr[kb] = *(const bf16x8*)(qg + kb * 32 + quad * 8);

  float m_r[4], l_r[4];
#pragma unroll
  for (int r = 0; r < 4; ++r) { m_r[r] = -1e30f; l_r[r] = 0.f; }
  floatx4 acc_o[8];
#pragma unroll
  for (int i = 0; i < 8; ++i) acc_o[i] = (floatx4)0.f;
  int srow_base = s0 + wave * 16 + quad * 4;

  const unsigned short* kg0 = kbuf + (size_t)hk * S_LEN * HD;
  const unsigned short* vg0 = vTb + (size_t)hk * HD * S_LEN;

  int kr4 = lane >> 4, kc16 = lane & 15;
  int vr8 = lane >> 3, vc8 = lane & 7;

  for (int t = 0; t <= qt; ++t) {
    int jt = t * 64;
#pragma unroll
    for (int i = 0; i < 4; ++i) {
      int rbase = wave * 16 + i * 4;
      int row = rbase + kr4;
      int cs = kc16 ^ (row & 7);
      async_copy16(kg0 + (size_t)(jt + row) * HD + cs * 8, Ks + rbase * 128);
    }
#pragma unroll
    for (int i = 0; i < 4; ++i) {
      int rbase = wave * 32 + i * 8;
      int row = rbase + vr8;
      int cs = vc8 ^ (row & 7);
      async_copy16(vg0 + (size_t)row * S_LEN + jt + cs * 8, Vs + rbase * 64);
    }
    __syncthreads();

    floatx4 acc_s[4];
#pragma unroll
    for (int ni = 0; ni < 4; ++ni) acc_s[ni] = (floatx4)0.f;
#pragma unroll
    for (int kb = 0; kb < 4; ++kb) {
#pragma unroll
      for (int ni = 0; ni < 4; ++ni) {
        int cl = (kb * 4 + quad) ^ lsw;
        bf16x8 bk = *(const bf16x8*)&Ks[(ni * 16 + l16) * 128 + cl * 8];
        acc_s[ni] = __builtin_amdgcn_mfma_f32_16x16x32_bf16(qfr[kb], bk, acc_s[ni], 0, 0, 0);
      }
    }

    bool diag = (t == qt);
    float alpha[4];
#pragma unroll
    for (int r = 0; r < 4; ++r) {
      float scv[4];
      float mx = -1e30f;
#pragma unroll
      for (int ni = 0; ni < 4; ++ni) {
        float sv = acc_s[ni][r] * SCALE;
        if (diag) {
          int jg = jt + ni * 16 + l16;
          if (jg > srow_base + r) sv = -1e30f;
        }
        scv[ni] = sv;
        mx = fmaxf(mx, sv);
      }
#pragma unroll
      for (int off = 8; off; off >>= 1) mx = fmaxf(mx, __shfl_xor(mx, off, 16));
      float mnew = fmaxf(m_r[r], mx);
      float psv = 0.f;
#pragma unroll
      for (int ni = 0; ni < 4; ++ni) {
        float pv = (scv[ni] > -1e29f) ? __expf(scv[ni] - mnew) : 0.f;
        Ps[wave][quad * 4 + r][ni * 16 + l16] = f2bf(pv);
        psv += pv;
      }
#pragma unroll
      for (int off = 8; off; off >>= 1) psv += __shfl_xor(psv, off, 16);
      alpha[r] = __expf(m_r[r] - mnew);
      m_r[r] = mnew;
      l_r[r] = l_r[r] * alpha[r] + psv;
    }
#pragma unroll
    for (int i = 0; i < 8; ++i)
#pragma unroll
      for (int r = 0; r < 4; ++r) acc_o[i][r] *= alpha[r];
    __threadfence_block();

#pragma unroll
    for (int kb2 = 0; kb2 < 2; ++kb2) {
      bf16x8 ap = *(const bf16x8*)&Ps[wave][l16][kb2 * 32 + quad * 8];
#pragma unroll
      for (int ni2 = 0; ni2 < 8; ++ni2) {
        int cl = (kb2 * 4 + quad) ^ lsw;
        bf16x8 bv = *(const bf16x8*)&Vs[(ni2 * 16 + l16) * 64 + cl * 8];
        acc_o[ni2] = __builtin_amdgcn_mfma_f32_16x16x32_bf16(ap, bv, acc_o[ni2], 0, 0, 0);
      }
    }
    __syncthreads();
  }

#pragma unroll
  for (int r = 0; r < 4; ++r) {
    int s = srow_base + r;
    float inv = 1.0f / l_r[r];
    const unsigned short* sgp = sgb + ((size_t)h * S_LEN + s) * HD;
    unsigned short* op = outT + (size_t)s * (NH * HD) + h * HD;
#pragma unroll
    for (int ni2 = 0; ni2 < 8; ++ni2) {
      int d = ni2 * 16 + l16;
      op[d] = f2bf(acc_o[ni2][r] * inv * bf2f(sgp[d]));
    }
  }
}

// ---------------- host launch ----------------
extern "C" void kernel_launch(void* const* d_in, const int* in_sizes, int n_in,
                              void* d_out, int out_size, void* d_ws, size_t ws_size,
                              hipStream_t stream) {
  const float* hs       = (const float*)d_in[0];
  const float* q_proj_w = (const float*)d_in[1];
  const float* k_proj_w = (const float*)d_in[2];
  const float* v_proj_w = (const float*)d_in[3];
  const float* o_proj_w = (const float*)d_in[4];
  const float* q_norm_w = (const float*)d_in[5];
  const float* k_norm_w = (const float*)d_in[6];
  const int*   pos_ids  = (const int*)d_in[9];
  const float* cos_c    = (const float*)d_in[10];
  const float* sin_c    = (const float*)d_in[11];
  float* out = (float*)d_out;

  char* ws = (char*)d_ws;
  unsigned short* wqkv = (unsigned short*)(ws + 0);            // 5120x2048 bf16
  unsigned short* wo   = (unsigned short*)(ws + 20971520);     // 2048x2048 bf16
  unsigned short* xT   = (unsigned short*)(ws + 29360128);     // 1024x2048 bf16
  unsigned short* qb   = (unsigned short*)(ws + 33554432);     // 16x1024x128
  unsigned short* kbuf = (unsigned short*)(ws + 37748736);     // 4x1024x128
  unsigned short* vTb  = (unsigned short*)(ws + 38797312);     // 4x128x1024 (V^T)
  unsigned short* sgb  = (unsigned short*)(ws + 39845888);     // 16x1024x128
  unsigned short* aoT  = (unsigned short*)(ws + 44040192);     // 1024x2048
  float* oP            = (float*)(ws + 48234496);              // 2x2048x1024 f32

  cast_all_kernel<<<14336, 256, 0, stream>>>(q_proj_w, k_proj_w, v_proj_w, o_proj_w, wqkv);
  transpose_cast_x_kernel<<<dim3(32, 64), 256, 0, stream>>>(hs, xT);
  gemm_qkv_fused<<<dim3(16, 40), 256, 0, stream>>>(wqkv, xT, q_norm_w, k_norm_w,
                                                   pos_ids, cos_c, sin_c,
                                                   qb, kbuf, vTb, sgb);
  attn_kernel<<<dim3(16, 16), 256, 0, stream>>>(qb, kbuf, vTb, sgb, aoT);
  gemm_oproj_sk<<<dim3(16, 16, 2), 256, 0, stream>>>(wo, aoT, oP);
  reduce_oproj_kernel<<<2048, 256, 0, stream>>>(oP, out);
}

// Round 8
// 245.435 us; speedup vs baseline: 1.0648x; 1.0648x over previous
//
#include <hip/hip_runtime.h>
#include <cstdint>

#define S_LEN 1024
#define C_DIM 2048
#define NH    16
#define NHK   4
#define HD    128
#define ROT   32
#define SCALE 0.08838834764831845f  // 1/sqrt(128)

typedef __bf16 bf16x8 __attribute__((ext_vector_type(8)));
typedef float floatx4 __attribute__((ext_vector_type(4)));
typedef float floatx16 __attribute__((ext_vector_type(16)));
typedef unsigned short ushortx8 __attribute__((ext_vector_type(8)));

__device__ __forceinline__ unsigned short f2bf(float f) {
  union { float f; uint32_t u; } x; x.f = f;
  uint32_t r = (x.u + 0x7fffu + ((x.u >> 16) & 1u)) >> 16;
  return (unsigned short)r;
}
__device__ __forceinline__ float bf2f(unsigned short v) {
  union { uint32_t u; float f; } x; x.u = (uint32_t)v << 16; return x.f;
}

__device__ __forceinline__ void async_copy16(const unsigned short* g, unsigned short* l) {
  __builtin_amdgcn_global_load_lds(
      (const __attribute__((address_space(1))) void*)g,
      (__attribute__((address_space(3))) void*)l,
      16, 0, 0);
}

// ---------------- fused weight cast f32 -> bf16 ----------------
__global__ void cast_all_kernel(const float* __restrict__ qw, const float* __restrict__ kw,
                                const float* __restrict__ vw, const float* __restrict__ ow,
                                unsigned short* __restrict__ out) {
  const int NQ = 4096 * 2048 / 4, NK = 512 * 2048 / 4, NV = 512 * 2048 / 4;
  int i = blockIdx.x * blockDim.x + threadIdx.x;
  const float* src; int j;
  if (i < NQ) { src = qw; j = i; }
  else if (i < NQ + NK) { src = kw; j = i - NQ; }
  else if (i < NQ + NK + NV) { src = vw; j = i - NQ - NK; }
  else { src = ow; j = i - NQ - NK - NV; }
  float4 v = ((const float4*)src)[j];
  ushort4 o;
  o.x = f2bf(v.x); o.y = f2bf(v.y); o.z = f2bf(v.z); o.w = f2bf(v.w);
  ((ushort4*)out)[i] = o;
}

// ---------------- transpose + cast x (C,S) -> xT (S,C) bf16 ----------------
__global__ __launch_bounds__(256)
void transpose_cast_x_kernel(const float* __restrict__ x, unsigned short* __restrict__ xT) {
  __shared__ float t[32][33];
  int st = blockIdx.x, ct = blockIdx.y;
  int c = threadIdx.x & 31, rq = threadIdx.x >> 5;
#pragma unroll
  for (int i = 0; i < 4; ++i) {
    int r = rq + i * 8;
    t[r][c] = x[(size_t)(ct * 32 + r) * S_LEN + st * 32 + c];
  }
  __syncthreads();
#pragma unroll
  for (int i = 0; i < 4; ++i) {
    int r = rq + i * 8;
    xT[(size_t)(st * 32 + r) * C_DIM + ct * 32 + c] = f2bf(t[c][r]);
  }
}

// ---------------- RMSNorm+RoPE epilogue (32x32 C/D layout, 1 ni) ------------
__device__ __forceinline__ void norm_rope_epi(
    floatx16 (&acc)[2], float (*pp)[32],
    const float* __restrict__ w, const int* __restrict__ pos_ids,
    const float* __restrict__ cosc, const float* __restrict__ sinc,
    unsigned short* __restrict__ outp,  // (S, D) for this head
    int wave, int lane, int wm, int scol0) {
  int l31 = lane & 31, half = lane >> 5;
  float s = 0.f;
#pragma unroll
  for (int mi = 0; mi < 2; ++mi)
#pragma unroll
    for (int reg = 0; reg < 16; ++reg) { float v = acc[mi][reg]; s += v * v; }
  s += __shfl_xor(s, 32);
  if (half == 0) pp[wave][l31] = s;
  __syncthreads();
  float rn = rsqrtf((pp[wave][l31] + pp[wave ^ 1][l31]) * (1.0f / 128.0f) + 1e-6f);
  int scol = scol0 + l31;
  int pos = pos_ids[scol];
#pragma unroll
  for (int mi = 0; mi < 2; ++mi) {
    bool rope = (wm == 0) && (mi == 0);
#pragma unroll
    for (int g = 0; g < 4; ++g) {
      int dbase = wm + mi * 32 + half * 4 + g * 8;
      ushort4 o;
#pragma unroll
      for (int rr = 0; rr < 4; ++rr) {
        int reg = g * 4 + rr;
        int d = dbase + rr;
        float v = acc[mi][reg] * rn * (1.0f + w[d]);
        if (rope) {
          float cv = cosc[pos * ROT + d], sv = sinc[pos * ROT + d];
          int d2 = (d < 16) ? d + 16 : d - 16;
          float pv = acc[mi][reg ^ 8] * rn * (1.0f + w[d2]);
          v = v * cv + ((d < 16) ? -pv : pv) * sv;
        }
        ((unsigned short*)&o)[rr] = f2bf(v);
      }
      *(ushort4*)&outp[(size_t)scol * HD + dbase] = o;
    }
  }
}

// ---------------- QKV GEMM 128x64, register-prefetch pipeline ---------------
// Grid dim3(40,16): x = M-tile (40%8==0 -> all N-blocks of an M-tile share an
// XCD; A-tile L2-resident, reused 16x).
// Staging: load NATURAL chunk c8 (coalesced), ds_write to SWIZZLED position
// c8^(row&7); MFMA readers un-swizzle with chunk^(l31&7). (Round-7 bug: loaded
// swizzled source AND wrote swizzled position -> identity layout vs XOR reads.)
__global__ __launch_bounds__(256, 4)
void gemm_qkv_fused(const unsigned short* __restrict__ A,
                    const unsigned short* __restrict__ BT,
                    const float* __restrict__ qw, const float* __restrict__ kw,
                    const int* __restrict__ pos_ids,
                    const float* __restrict__ cosc, const float* __restrict__ sinc,
                    unsigned short* __restrict__ qb, unsigned short* __restrict__ kbuf,
                    unsigned short* __restrict__ vTb, unsigned short* __restrict__ sgb) {
  __shared__ unsigned short Asm[2][128 * 64];
  __shared__ unsigned short Bsm[2][64 * 64];
  __shared__ float pp[4][32];
  int tid = threadIdx.x, wave = tid >> 6, lane = tid & 63;
  int l31 = lane & 31, half = lane >> 5;
  int wm = (wave & 1) * 64, wn = (wave >> 1) * 32;
  int m0 = blockIdx.x * 128, n0 = blockIdx.y * 64;
  int r8 = lane >> 3, c8 = lane & 7;
  int arow[4], brow[2], apos[4], bpos[2];
#pragma unroll
  for (int i = 0; i < 4; ++i) { arow[i] = wave * 32 + i * 8 + r8; apos[i] = c8 ^ (arow[i] & 7); }
#pragma unroll
  for (int i = 0; i < 2; ++i) { brow[i] = wave * 16 + i * 8 + r8; bpos[i] = c8 ^ (brow[i] & 7); }
  const unsigned short* Ag = A + (size_t)m0 * C_DIM;
  const unsigned short* Bg = BT + (size_t)n0 * C_DIM;
  floatx16 acc[2];
  acc[0] = (floatx16)0.f; acc[1] = (floatx16)0.f;
  ushortx8 rA[4], rB[2];

  // prologue: tile 0 -> buf 0
#pragma unroll
  for (int i = 0; i < 4; ++i) rA[i] = *(const ushortx8*)(Ag + (size_t)arow[i] * C_DIM + c8 * 8);
#pragma unroll
  for (int i = 0; i < 2; ++i) rB[i] = *(const ushortx8*)(Bg + (size_t)brow[i] * C_DIM + c8 * 8);
#pragma unroll
  for (int i = 0; i < 4; ++i) *(ushortx8*)&Asm[0][arow[i] * 64 + apos[i] * 8] = rA[i];
#pragma unroll
  for (int i = 0; i < 2; ++i) *(ushortx8*)&Bsm[0][brow[i] * 64 + bpos[i] * 8] = rB[i];
  __syncthreads();

  for (int t = 0; t < 32; ++t) {
    int b = t & 1;
    if (t < 31) {   // issue t+1 global loads; they fly during compute
      int kt = (t + 1) * 64;
#pragma unroll
      for (int i = 0; i < 4; ++i) rA[i] = *(const ushortx8*)(Ag + (size_t)arow[i] * C_DIM + kt + c8 * 8);
#pragma unroll
      for (int i = 0; i < 2; ++i) rB[i] = *(const ushortx8*)(Bg + (size_t)brow[i] * C_DIM + kt + c8 * 8);
    }
#pragma unroll
    for (int kb = 0; kb < 4; ++kb) {
      int co = (((kb << 1) | half) ^ (l31 & 7)) << 3;
      bf16x8 a0 = *(const bf16x8*)&Asm[b][(wm + l31) * 64 + co];
      bf16x8 a1 = *(const bf16x8*)&Asm[b][(wm + 32 + l31) * 64 + co];
      bf16x8 bf = *(const bf16x8*)&Bsm[b][(wn + l31) * 64 + co];
      acc[0] = __builtin_amdgcn_mfma_f32_32x32x16_bf16(a0, bf, acc[0], 0, 0, 0);
      acc[1] = __builtin_amdgcn_mfma_f32_32x32x16_bf16(a1, bf, acc[1], 0, 0, 0);
    }
    if (t < 31) {
#pragma unroll
      for (int i = 0; i < 4; ++i) *(ushortx8*)&Asm[b ^ 1][arow[i] * 64 + apos[i] * 8] = rA[i];
#pragma unroll
      for (int i = 0; i < 2; ++i) *(ushortx8*)&Bsm[b ^ 1][brow[i] * 64 + bpos[i] * 8] = rB[i];
    }
    __syncthreads();
  }

  int scol0 = n0 + wn;
  int ty = blockIdx.x;
  if (ty < 32) {
    int h = ty >> 1;
    if ((ty & 1) == 0) {
      norm_rope_epi(acc, pp, qw, pos_ids, cosc, sinc,
                    qb + (size_t)h * S_LEN * HD, wave, lane, wm, scol0);
    } else {
      int scol = scol0 + l31;
#pragma unroll
      for (int mi = 0; mi < 2; ++mi)
#pragma unroll
        for (int g = 0; g < 4; ++g) {
          int dbase = wm + mi * 32 + half * 4 + g * 8;
          ushort4 o;
#pragma unroll
          for (int rr = 0; rr < 4; ++rr)
            ((unsigned short*)&o)[rr] = f2bf(1.0f / (1.0f + __expf(-acc[mi][g * 4 + rr])));
          *(ushort4*)&sgb[((size_t)h * S_LEN + scol) * HD + dbase] = o;
        }
    }
  } else if (ty < 36) {
    int hk = ty - 32;
    norm_rope_epi(acc, pp, kw, pos_ids, cosc, sinc,
                  kbuf + (size_t)hk * S_LEN * HD, wave, lane, wm, scol0);
  } else {
    int hk = ty - 36;  // v: rows are d, cols are s -> vTb (hk,D,S)
#pragma unroll
    for (int mi = 0; mi < 2; ++mi)
#pragma unroll
      for (int reg = 0; reg < 16; ++reg) {
        int d = wm + mi * 32 + (reg & 3) + 8 * (reg >> 2) + 4 * half;
        vTb[(size_t)hk * HD * S_LEN + (size_t)d * S_LEN + scol0 + l31] = f2bf(acc[mi][reg]);
      }
  }
}

// ---------------- O-proj GEMM 128x64, same pipeline, direct f32 out ---------
__global__ __launch_bounds__(256, 4)
void gemm_oproj(const unsigned short* __restrict__ A,
                const unsigned short* __restrict__ BT,
                float* __restrict__ C) {
  __shared__ unsigned short Asm[2][128 * 64];
  __shared__ unsigned short Bsm[2][64 * 64];
  int tid = threadIdx.x, wave = tid >> 6, lane = tid & 63;
  int l31 = lane & 31, half = lane >> 5;
  int wm = (wave & 1) * 64, wn = (wave >> 1) * 32;
  int m0 = blockIdx.x * 128, n0 = blockIdx.y * 64;
  int r8 = lane >> 3, c8 = lane & 7;
  int arow[4], brow[2], apos[4], bpos[2];
#pragma unroll
  for (int i = 0; i < 4; ++i) { arow[i] = wave * 32 + i * 8 + r8; apos[i] = c8 ^ (arow[i] & 7); }
#pragma unroll
  for (int i = 0; i < 2; ++i) { brow[i] = wave * 16 + i * 8 + r8; bpos[i] = c8 ^ (brow[i] & 7); }
  const unsigned short* Ag = A + (size_t)m0 * C_DIM;
  const unsigned short* Bg = BT + (size_t)n0 * C_DIM;
  floatx16 acc[2];
  acc[0] = (floatx16)0.f; acc[1] = (floatx16)0.f;
  ushortx8 rA[4], rB[2];

#pragma unroll
  for (int i = 0; i < 4; ++i) rA[i] = *(const ushortx8*)(Ag + (size_t)arow[i] * C_DIM + c8 * 8);
#pragma unroll
  for (int i = 0; i < 2; ++i) rB[i] = *(const ushortx8*)(Bg + (size_t)brow[i] * C_DIM + c8 * 8);
#pragma unroll
  for (int i = 0; i < 4; ++i) *(ushortx8*)&Asm[0][arow[i] * 64 + apos[i] * 8] = rA[i];
#pragma unroll
  for (int i = 0; i < 2; ++i) *(ushortx8*)&Bsm[0][brow[i] * 64 + bpos[i] * 8] = rB[i];
  __syncthreads();

  for (int t = 0; t < 32; ++t) {
    int b = t & 1;
    if (t < 31) {
      int kt = (t + 1) * 64;
#pragma unroll
      for (int i = 0; i < 4; ++i) rA[i] = *(const ushortx8*)(Ag + (size_t)arow[i] * C_DIM + kt + c8 * 8);
#pragma unroll
      for (int i = 0; i < 2; ++i) rB[i] = *(const ushortx8*)(Bg + (size_t)brow[i] * C_DIM + kt + c8 * 8);
    }
#pragma unroll
    for (int kb = 0; kb < 4; ++kb) {
      int co = (((kb << 1) | half) ^ (l31 & 7)) << 3;
      bf16x8 a0 = *(const bf16x8*)&Asm[b][(wm + l31) * 64 + co];
      bf16x8 a1 = *(const bf16x8*)&Asm[b][(wm + 32 + l31) * 64 + co];
      bf16x8 bf = *(const bf16x8*)&Bsm[b][(wn + l31) * 64 + co];
      acc[0] = __builtin_amdgcn_mfma_f32_32x32x16_bf16(a0, bf, acc[0], 0, 0, 0);
      acc[1] = __builtin_amdgcn_mfma_f32_32x32x16_bf16(a1, bf, acc[1], 0, 0, 0);
    }
    if (t < 31) {
#pragma unroll
      for (int i = 0; i < 4; ++i) *(ushortx8*)&Asm[b ^ 1][arow[i] * 64 + apos[i] * 8] = rA[i];
#pragma unroll
      for (int i = 0; i < 2; ++i) *(ushortx8*)&Bsm[b ^ 1][brow[i] * 64 + bpos[i] * 8] = rB[i];
    }
    __syncthreads();
  }
#pragma unroll
  for (int mi = 0; mi < 2; ++mi)
#pragma unroll
    for (int reg = 0; reg < 16; ++reg) {
      int row = m0 + wm + mi * 32 + (reg & 3) + 8 * (reg >> 2) + 4 * half;
      C[(size_t)row * S_LEN + n0 + wn + l31] = acc[mi][reg];
    }
}

// ---------------- MFMA flash attention, LDS-staged, 64 queries/block --------
__global__ __launch_bounds__(256)
void attn_kernel(const unsigned short* __restrict__ qb,
                 const unsigned short* __restrict__ kbuf,
                 const unsigned short* __restrict__ vTb,
                 const unsigned short* __restrict__ sgb,
                 unsigned short* __restrict__ outT) {
  __shared__ __align__(16) unsigned short Ks[64 * 128];   // [key][d], swizzled
  __shared__ __align__(16) unsigned short Vs[128 * 64];   // [d][key], swizzled
  __shared__ __align__(16) unsigned short Ps[4][16][72];
  int h = blockIdx.x, qt = blockIdx.y;
  int s0 = qt * 64;
  int hk = h >> 2;
  int tid = threadIdx.x, wave = tid >> 6, lane = tid & 63;
  int l16 = lane & 15, quad = lane >> 4;
  int lsw = l16 & 7;

  const unsigned short* qg = qb + ((size_t)(h * S_LEN + s0 + wave * 16 + l16)) * HD;
  bf16x8 qfr[4];
#pragma unroll
  for (int kb = 0; kb < 4; ++kb)
    qfr[kb] = *(const bf16x8*)(qg + kb * 32 + quad * 8);

  float m_r[4], l_r[4];
#pragma unroll
  for (int r = 0; r < 4; ++r) { m_r[r] = -1e30f; l_r[r] = 0.f; }
  floatx4 acc_o[8];
#pragma unroll
  for (int i = 0; i < 8; ++i) acc_o[i] = (floatx4)0.f;
  int srow_base = s0 + wave * 16 + quad * 4;

  const unsigned short* kg0 = kbuf + (size_t)hk * S_LEN * HD;
  const unsigned short* vg0 = vTb + (size_t)hk * HD * S_LEN;

  int kr4 = lane >> 4, kc16 = lane & 15;
  int vr8 = lane >> 3, vc8 = lane & 7;

  for (int t = 0; t <= qt; ++t) {
    int jt = t * 64;
#pragma unroll
    for (int i = 0; i < 4; ++i) {
      int rbase = wave * 16 + i * 4;
      int row = rbase + kr4;
      int cs = kc16 ^ (row & 7);
      async_copy16(kg0 + (size_t)(jt + row) * HD + cs * 8, Ks + rbase * 128);
    }
#pragma unroll
    for (int i = 0; i < 4; ++i) {
      int rbase = wave * 32 + i * 8;
      int row = rbase + vr8;
      int cs = vc8 ^ (row & 7);
      async_copy16(vg0 + (size_t)row * S_LEN + jt + cs * 8, Vs + rbase * 64);
    }
    __syncthreads();

    floatx4 acc_s[4];
#pragma unroll
    for (int ni = 0; ni < 4; ++ni) acc_s[ni] = (floatx4)0.f;
#pragma unroll
    for (int kb = 0; kb < 4; ++kb) {
#pragma unroll
      for (int ni = 0; ni < 4; ++ni) {
        int cl = (kb * 4 + quad) ^ lsw;
        bf16x8 bk = *(const bf16x8*)&Ks[(ni * 16 + l16) * 128 + cl * 8];
        acc_s[ni] = __builtin_amdgcn_mfma_f32_16x16x32_bf16(qfr[kb], bk, acc_s[ni], 0, 0, 0);
      }
    }

    bool diag = (t == qt);
    float alpha[4];
#pragma unroll
    for (int r = 0; r < 4; ++r) {
      float scv[4];
      float mx = -1e30f;
#pragma unroll
      for (int ni = 0; ni < 4; ++ni) {
        float sv = acc_s[ni][r] * SCALE;
        if (diag) {
          int jg = jt + ni * 16 + l16;
          if (jg > srow_base + r) sv = -1e30f;
        }
        scv[ni] = sv;
        mx = fmaxf(mx, sv);
      }
#pragma unroll
      for (int off = 8; off; off >>= 1) mx = fmaxf(mx, __shfl_xor(mx, off, 16));
      float mnew = fmaxf(m_r[r], mx);
      float psv = 0.f;
#pragma unroll
      for (int ni = 0; ni < 4; ++ni) {
        float pv = (scv[ni] > -1e29f) ? __expf(scv[ni] - mnew) : 0.f;
        Ps[wave][quad * 4 + r][ni * 16 + l16] = f2bf(pv);
        psv += pv;
      }
#pragma unroll
      for (int off = 8; off; off >>= 1) psv += __shfl_xor(psv, off, 16);
      alpha[r] = __expf(m_r[r] - mnew);
      m_r[r] = mnew;
      l_r[r] = l_r[r] * alpha[r] + psv;
    }
#pragma unroll
    for (int i = 0; i < 8; ++i)
#pragma unroll
      for (int r = 0; r < 4; ++r) acc_o[i][r] *= alpha[r];
    __threadfence_block();

#pragma unroll
    for (int kb2 = 0; kb2 < 2; ++kb2) {
      bf16x8 ap = *(const bf16x8*)&Ps[wave][l16][kb2 * 32 + quad * 8];
#pragma unroll
      for (int ni2 = 0; ni2 < 8; ++ni2) {
        int cl = (kb2 * 4 + quad) ^ lsw;
        bf16x8 bv = *(const bf16x8*)&Vs[(ni2 * 16 + l16) * 64 + cl * 8];
        acc_o[ni2] = __builtin_amdgcn_mfma_f32_16x16x32_bf16(ap, bv, acc_o[ni2], 0, 0, 0);
      }
    }
    __syncthreads();
  }

#pragma unroll
  for (int r = 0; r < 4; ++r) {
    int s = srow_base + r;
    float inv = 1.0f / l_r[r];
    const unsigned short* sgp = sgb + ((size_t)h * S_LEN + s) * HD;
    unsigned short* op = outT + (size_t)s * (NH * HD) + h * HD;
#pragma unroll
    for (int ni2 = 0; ni2 < 8; ++ni2) {
      int d = ni2 * 16 + l16;
      op[d] = f2bf(acc_o[ni2][r] * inv * bf2f(sgp[d]));
    }
  }
}

// ---------------- host launch ----------------
extern "C" void kernel_launch(void* const* d_in, const int* in_sizes, int n_in,
                              void* d_out, int out_size, void* d_ws, size_t ws_size,
                              hipStream_t stream) {
  const float* hs       = (const float*)d_in[0];
  const float* q_proj_w = (const float*)d_in[1];
  const float* k_proj_w = (const float*)d_in[2];
  const float* v_proj_w = (const float*)d_in[3];
  const float* o_proj_w = (const float*)d_in[4];
  const float* q_norm_w = (const float*)d_in[5];
  const float* k_norm_w = (const float*)d_in[6];
  const int*   pos_ids  = (const int*)d_in[9];
  const float* cos_c    = (const float*)d_in[10];
  const float* sin_c    = (const float*)d_in[11];
  float* out = (float*)d_out;

  char* ws = (char*)d_ws;
  unsigned short* wqkv = (unsigned short*)(ws + 0);            // 5120x2048 bf16
  unsigned short* wo   = (unsigned short*)(ws + 20971520);     // 2048x2048 bf16
  unsigned short* xT   = (unsigned short*)(ws + 29360128);     // 1024x2048 bf16
  unsigned short* qb   = (unsigned short*)(ws + 33554432);     // 16x1024x128
  unsigned short* kbuf = (unsigned short*)(ws + 37748736);     // 4x1024x128
  unsigned short* vTb  = (unsigned short*)(ws + 38797312);     // 4x128x1024 (V^T)
  unsigned short* sgb  = (unsigned short*)(ws + 39845888);     // 16x1024x128
  unsigned short* aoT  = (unsigned short*)(ws + 44040192);     // 1024x2048

  cast_all_kernel<<<14336, 256, 0, stream>>>(q_proj_w, k_proj_w, v_proj_w, o_proj_w, wqkv);
  transpose_cast_x_kernel<<<dim3(32, 64), 256, 0, stream>>>(hs, xT);
  gemm_qkv_fused<<<dim3(40, 16), 256, 0, stream>>>(wqkv, xT, q_norm_w, k_norm_w,
                                                   pos_ids, cos_c, sin_c,
                                                   qb, kbuf, vTb, sgb);
  attn_kernel<<<dim3(16, 16), 256, 0, stream>>>(qb, kbuf, vTb, sgb, aoT);
  gemm_oproj<<<dim3(16, 16), 256, 0, stream>>>(wo, aoT, out);
}